// Round 6
// baseline (443.746 us; speedup 1.0000x reference)
//
#include <hip/hip_runtime.h>
#include <math.h>

// MultiHeadAttention: B=2, S=2048, HIDDEN=2048, NH=16, HD=128
constexpr int S_LEN = 2048;
constexpr int HID   = 2048;
constexpr int NH    = 16;
constexpr int HD    = 128;

typedef __attribute__((ext_vector_type(8))) short short8;   // 8 bf16 = MFMA A/B frag
typedef __attribute__((ext_vector_type(4))) float floatx4;  // MFMA C/D frag

static __device__ __forceinline__ ushort f2bf(float f) {
  union { float f; unsigned u; } v; v.f = f;
  unsigned r = (v.u + 0x7fffu + ((v.u >> 16) & 1u)) >> 16;  // RNE
  return (ushort)r;
}
static __device__ __forceinline__ ushort f2bf_fast(float f) {
  union { float f; unsigned u; } v; v.f = f;
  return (ushort)((v.u + 0x8000u) >> 16);  // round-to-nearest (ties away)
}

// async global->LDS, 16 B per lane; LDS dest = uniform base + lane*16
static __device__ __forceinline__ void glds16(const ushort* g, ushort* l) {
  __builtin_amdgcn_global_load_lds(
      (const __attribute__((address_space(1))) void*)g,
      (__attribute__((address_space(3))) void*)l, 16, 0, 0);
}

// ---------------------------------------------------------------------------
// Conversion pre-pass: xb=bf16(x); Wq/Wk/Wv/Wo -> bf16.
// ---------------------------------------------------------------------------
static __device__ __forceinline__ void cvt4(ushort* dst, const float* src, size_t i) {
  const float4 v = ((const float4*)src)[i];
  ushort4 u = {f2bf(v.x), f2bf(v.y), f2bf(v.z), f2bf(v.w)};
  ((ushort4*)dst)[i] = u;
}

__global__ __launch_bounds__(256)
void convert_all(const float* __restrict__ x,
                 const float* __restrict__ wq, const float* __restrict__ wk,
                 const float* __restrict__ wv, const float* __restrict__ wo,
                 ushort* __restrict__ xb, ushort* __restrict__ wqb,
                 ushort* __restrict__ wkb, ushort* __restrict__ wvb,
                 ushort* __restrict__ wob) {
  const size_t gid = blockIdx.x * 256 + threadIdx.x;
  const size_t T = gridDim.x * 256;
  const size_t NX = (size_t)4096 * HID / 4;   // 2M float4
  const size_t NW = (size_t)HID * HID / 4;    // 1M float4
  for (size_t i = gid; i < NX; i += T) cvt4(xb, x, i);
  for (size_t i = gid; i < NW; i += T) {
    cvt4(wqb, wq, i);
    cvt4(wkb, wk, i);
    cvt4(wvb, wv, i);
    cvt4(wob, wo, i);
  }
}

// ---------------------------------------------------------------------------
// bf16 MFMA GEMM (m97 structure): C[m,n] = sum_k A[m,k]*W[n,k] + bias[n].
// 128x128 tile, BK=32, 256 thr (2x2 waves of 64x64), 16x16x32 MFMA.
// LDS [128][32] bf16, 16B chunks XOR-swizzled -> DMA-compatible + conflict-free.
// ---------------------------------------------------------------------------
template <bool BF16OUT>
__device__ __forceinline__
void gemm_core(const ushort* __restrict__ A, const ushort* __restrict__ W,
               const float* __restrict__ bias, void* __restrict__ Cv,
               int m0, int n0) {
  __shared__ __align__(16) ushort As[4096];   // 128x32
  __shared__ __align__(16) ushort Bs[4096];

  const int tid  = threadIdx.x;
  const int lane = tid & 63;
  const int w    = tid >> 6;
  const int wm   = w >> 1, wn = w & 1;
  const int n16  = lane & 15, q4 = lane >> 4;

  const int sr = lane >> 2;
  const int sc = (lane & 3) ^ ((lane >> 4) & 3);
  const ushort* ag0 = A + (size_t)(m0 + w*32 + sr) * HID + sc*8;
  const ushort* ag1 = ag0 + (size_t)16 * HID;
  const ushort* bg0 = W + (size_t)(n0 + w*32 + sr) * HID + sc*8;
  const ushort* bg1 = bg0 + (size_t)16 * HID;
  ushort* al0 = As + (w*2 + 0) * 512;
  ushort* al1 = As + (w*2 + 1) * 512;
  ushort* bl0 = Bs + (w*2 + 0) * 512;
  ushort* bl1 = Bs + (w*2 + 1) * 512;

  const int fp = n16*4 + (q4 ^ ((n16 >> 2) & 3));

  floatx4 acc[4][4];
  #pragma unroll
  for (int i = 0; i < 4; ++i)
    #pragma unroll
    for (int j = 0; j < 4; ++j) acc[i][j] = (floatx4)0.f;

  for (int kb0 = 0; kb0 < HID; kb0 += 32) {
    __syncthreads();
    glds16(ag0 + kb0, al0);
    glds16(ag1 + kb0, al1);
    glds16(bg0 + kb0, bl0);
    glds16(bg1 + kb0, bl1);
    __syncthreads();

    short8 af[4], bf[4];
    #pragma unroll
    for (int t = 0; t < 4; ++t) {
      af[t] = *(const short8*)&As[(wm*4 + t)*512 + fp*8];
      bf[t] = *(const short8*)&Bs[(wn*4 + t)*512 + fp*8];
    }
    #pragma unroll
    for (int mt = 0; mt < 4; ++mt)
      #pragma unroll
      for (int nt = 0; nt < 4; ++nt)
        acc[mt][nt] = __builtin_amdgcn_mfma_f32_16x16x32_bf16(af[mt], bf[nt], acc[mt][nt], 0, 0, 0);
  }

  float bv4[4];
  #pragma unroll
  for (int nt = 0; nt < 4; ++nt) bv4[nt] = bias[n0 + wn*64 + nt*16 + n16];
  #pragma unroll
  for (int mt = 0; mt < 4; ++mt)
    #pragma unroll
    for (int nt = 0; nt < 4; ++nt)
      #pragma unroll
      for (int r = 0; r < 4; ++r) {
        const int row = m0 + wm*64 + mt*16 + q4*4 + r;
        const int col = n0 + wn*64 + nt*16 + n16;
        if (BF16OUT)
          ((ushort*)Cv)[(size_t)row * HID + col] = f2bf(acc[mt][nt][r] + bv4[nt]);
        else
          ((float*)Cv)[(size_t)row * HID + col] = acc[mt][nt][r] + bv4[nt];
      }
}

__global__ __launch_bounds__(256)
void gemm_qkv(const ushort* __restrict__ xb,
              const ushort* __restrict__ wqb, const ushort* __restrict__ wkb,
              const ushort* __restrict__ wvb,
              const float* __restrict__ bq, const float* __restrict__ bk,
              const float* __restrict__ bv,
              ushort* __restrict__ qb, ushort* __restrict__ kb_, ushort* __restrict__ vb) {
  const ushort* W; const float* bias; ushort* C;
  if (blockIdx.z == 0)      { W = wqb; bias = bq; C = qb;  }
  else if (blockIdx.z == 1) { W = wkb; bias = bk; C = kb_; }
  else                      { W = wvb; bias = bv; C = vb;  }
  gemm_core<true>(xb, W, bias, C, blockIdx.y * 128, blockIdx.x * 128);
}

__global__ __launch_bounds__(256)
void gemm_o(const ushort* __restrict__ ao, const ushort* __restrict__ wob,
            const float* __restrict__ bo, float* __restrict__ out) {
  gemm_core<false>(ao, wob, bo, out, blockIdx.y * 128, blockIdx.x * 128);
}

// ---------------------------------------------------------------------------
// Flash attention v3: bf16 MFMA, fixed-max softmax, 32 q-rows PER WAVE (two
// m-frags -> K/V LDS reads per q-row halved), in-kernel V transpose staging
// (reads vb row-major, ds_write_b16 scatter; 4-way conflict = 1.58x, ~5us),
// register-prefetch double-buffered K/V. 256 thr / 4 waves / 128 q-rows.
// LDS: Ks 17.4K + Vs 18.4K + Ps 18.4K = 54.2 KB -> 2 blocks/CU.
// ---------------------------------------------------------------------------
__global__ __launch_bounds__(256, 2)
void attn_mfma(const ushort* __restrict__ qb, const ushort* __restrict__ kbuf,
               const ushort* __restrict__ vb, const float* __restrict__ mask,
               ushort* __restrict__ ao) {
  __shared__ __align__(16) ushort Ks[64 * 136];     // [kcol][d]   pitch 136
  __shared__ __align__(16) ushort Vs[128 * 72];     // [dd][c]     pitch 72
  __shared__ __align__(16) ushort Ps[4 * 32 * 72];  // per-wave [qrow 32][c]

  const int tid  = threadIdx.x;
  const int w    = tid >> 6;
  const int lane = tid & 63;
  const int n16  = lane & 15;
  const int q4   = lane >> 4;
  const int b  = blockIdx.y >> 4;
  const int h  = blockIdx.y & 15;
  const int q0 = blockIdx.x * 128;
  const float scale = 0.08838834764831845f;  // 1/sqrt(128)

  ushort* Pw = Ps + w * (32 * 72);

  // Q A-frags, resident whole kernel: mt in {0,1}, rows w*32 + mt*16 + n16
  short8 aq[2][4];
  #pragma unroll
  for (int mt = 0; mt < 2; ++mt) {
    const ushort* qrow = qb + (size_t)(b*S_LEN + q0 + w*32 + mt*16 + n16)*HID + h*HD;
    #pragma unroll
    for (int kc = 0; kc < 4; ++kc)
      aq[mt][kc] = *(const short8*)(qrow + kc*32 + q4*8);
  }

  floatx4 oacc[2][8];
  float lp[2][4];
  #pragma unroll
  for (int mt = 0; mt < 2; ++mt) {
    #pragma unroll
    for (int dt = 0; dt < 8; ++dt) oacc[mt][dt] = (floatx4)0.f;
    #pragma unroll
    for (int r = 0; r < 4; ++r) lp[mt][r] = 0.f;
  }

  // staging geometry (256 thr): thread covers 32 contiguous elems of one row
  const int srow = tid >> 2;            // 0..63 (k-col for K, c-row for V)
  const int sseg = (tid & 3) * 32;      // d-offset 0/32/64/96
  const ushort* kg = kbuf + (size_t)(b*S_LEN + srow)*HID + h*HD + sseg;
  const ushort* vg = vb   + (size_t)(b*S_LEN + srow)*HID + h*HD + sseg;

  // prefetch tile 0 (4 uint4 each = 32 bf16)
  uint4 kr[4], vr[4];
  #pragma unroll
  for (int j = 0; j < 4; ++j) {
    kr[j] = *(const uint4*)(kg + j*8);
    vr[j] = *(const uint4*)(vg + j*8);
  }

  for (int kb0 = 0; kb0 < S_LEN; kb0 += 64) {
    __syncthreads();  // prev tile's compute done
    // K: row-major, pitch 136
    #pragma unroll
    for (int j = 0; j < 4; ++j)
      *(uint4*)&Ks[srow*136 + sseg + j*8] = kr[j];
    // V: transpose scatter, Vs[d][c] <- vr (32 b16 writes)
    const ushort* vsc = (const ushort*)vr;
    #pragma unroll
    for (int j = 0; j < 32; ++j)
      Vs[(sseg + j)*72 + srow] = vsc[j];
    if (kb0 + 64 < S_LEN) {  // prefetch next tile; hides behind compute
      const size_t ko = (size_t)64 * HID;
      const ushort* kg2 = kg + (size_t)(kb0 + 64) * HID;
      const ushort* vg2 = vg + (size_t)(kb0 + 64) * HID;
      #pragma unroll
      for (int j = 0; j < 4; ++j) {
        kr[j] = *(const uint4*)(kg2 + j*8);
        vr[j] = *(const uint4*)(vg2 + j*8);
      }
      (void)ko;
    }
    __syncthreads();

    // QK^T: D[qrow 32][kcol 64]; K-frags read once, reused across 2 m-tiles
    floatx4 acc[2][4];
    #pragma unroll
    for (int mt = 0; mt < 2; ++mt)
      #pragma unroll
      for (int nt = 0; nt < 4; ++nt) acc[mt][nt] = (floatx4)0.f;
    #pragma unroll
    for (int nt = 0; nt < 4; ++nt) {
      #pragma unroll
      for (int kc = 0; kc < 4; ++kc) {
        const short8 bk = *(const short8*)&Ks[(nt*16 + n16)*136 + kc*32 + q4*8];
        acc[0][nt] = __builtin_amdgcn_mfma_f32_16x16x32_bf16(aq[0][kc], bk, acc[0][nt], 0, 0, 0);
        acc[1][nt] = __builtin_amdgcn_mfma_f32_16x16x32_bf16(aq[1][kc], bk, acc[1][nt], 0, 0, 0);
      }
    }

    // fixed-max softmax: p = exp(s*scale + mask); no reductions, no rescale
    float mk[4];
    #pragma unroll
    for (int nt = 0; nt < 4; ++nt)
      mk[nt] = mask[(size_t)b*S_LEN + kb0 + nt*16 + n16];

    #pragma unroll
    for (int mt = 0; mt < 2; ++mt)
      #pragma unroll
      for (int r = 0; r < 4; ++r) {
        float p[4];
        #pragma unroll
        for (int nt = 0; nt < 4; ++nt) p[nt] = __expf(acc[mt][nt][r] * scale + mk[nt]);
        lp[mt][r] += (p[0] + p[1]) + (p[2] + p[3]);
        #pragma unroll
        for (int nt = 0; nt < 4; ++nt)
          Pw[(mt*16 + q4*4 + r)*72 + nt*16 + n16] = f2bf_fast(p[nt]);
      }
    // per-wave Ps: same-wave write->read, compiler inserts lgkmcnt

    // PV: D[qrow 32][dd 128] += P[32x64] * V[64x128]; V-frags reused x2
    #pragma unroll
    for (int kc2 = 0; kc2 < 2; ++kc2) {
      const short8 ap0 = *(const short8*)&Pw[(0*16 + n16)*72 + kc2*32 + q4*8];
      const short8 ap1 = *(const short8*)&Pw[(1*16 + n16)*72 + kc2*32 + q4*8];
      #pragma unroll
      for (int dt = 0; dt < 8; ++dt) {
        const short8 bvf = *(const short8*)&Vs[(dt*16 + n16)*72 + kc2*32 + q4*8];
        oacc[0][dt] = __builtin_amdgcn_mfma_f32_16x16x32_bf16(ap0, bvf, oacc[0][dt], 0, 0, 0);
        oacc[1][dt] = __builtin_amdgcn_mfma_f32_16x16x32_bf16(ap1, bvf, oacc[1][dt], 0, 0, 0);
      }
    }
  }

  // one-time l reduction across the 16 lanes sharing each row
  #pragma unroll
  for (int mt = 0; mt < 2; ++mt)
    #pragma unroll
    for (int r = 0; r < 4; ++r) {
      float l = lp[mt][r];
      l += __shfl_xor(l, 1);
      l += __shfl_xor(l, 2);
      l += __shfl_xor(l, 4);
      l += __shfl_xor(l, 8);
      lp[mt][r] = 1.0f / l;
    }

  #pragma unroll
  for (int mt = 0; mt < 2; ++mt)
    #pragma unroll
    for (int r = 0; r < 4; ++r) {
      const size_t rowoff = (size_t)(b*S_LEN + q0 + w*32 + mt*16 + q4*4 + r)*HID + h*HD;
      #pragma unroll
      for (int dt = 0; dt < 8; ++dt)
        ao[rowoff + dt*16 + n16] = f2bf(oacc[mt][dt][r] * lp[mt][r]);
    }
}

// ---------------------------------------------------------------------------
extern "C" void kernel_launch(void* const* d_in, const int* in_sizes, int n_in,
                              void* d_out, int out_size, void* d_ws, size_t ws_size,
                              hipStream_t stream) {
  (void)n_in; (void)out_size; (void)ws_size;
  const float* x    = (const float*)d_in[0];
  const float* mask = (const float*)d_in[1];
  const float* Wq   = (const float*)d_in[2];
  const float* bq   = (const float*)d_in[3];
  const float* Wk   = (const float*)d_in[4];
  const float* bk   = (const float*)d_in[5];
  const float* Wv   = (const float*)d_in[6];
  const float* bv   = (const float*)d_in[7];
  const float* Wo   = (const float*)d_in[8];
  const float* bo   = (const float*)d_in[9];
  float* out = (float*)d_out;

  const int B = in_sizes[0] / (S_LEN * HID);   // 2
  const int M = B * S_LEN;                     // 4096
  const size_t MH = (size_t)M * HID;           // 8M
  const size_t WW = (size_t)HID * HID;         // 4M

  // ws layout (96 MB): xb | wqb wkb wvb wob | qb kbuf vb
  ushort* xb   = (ushort*)d_ws;       // 8M
  ushort* wqb  = xb   + MH;           // 4M each
  ushort* wkb  = wqb  + WW;
  ushort* wvb  = wkb  + WW;
  ushort* wob  = wvb  + WW;
  ushort* qb   = wob  + WW;           // 8M each
  ushort* kbuf = qb   + MH;
  ushort* vb   = kbuf + MH;
  ushort* ao   = xb;                  // xb dead after gemm_qkv

  convert_all<<<512, 256, 0, stream>>>(x, Wq, Wk, Wv, Wo, xb, wqb, wkb, wvb, wob);
  gemm_qkv<<<dim3(HID/128, M/128, 3), 256, 0, stream>>>(xb, wqb, wkb, wvb, bq, bk, bv, qb, kbuf, vb);
  attn_mfma<<<dim3(S_LEN/128, B*NH), 256, 0, stream>>>(qb, kbuf, vb, mask, ao);
  gemm_o<<<dim3(HID/128, M/128), 256, 0, stream>>>(ao, wob, bo, out);
}

// Round 7
// 416.640 us; speedup vs baseline: 1.0651x; 1.0651x over previous
//
#include <hip/hip_runtime.h>
#include <math.h>

// MultiHeadAttention: B=2, S=2048, HIDDEN=2048, NH=16, HD=128
constexpr int S_LEN = 2048;
constexpr int HID   = 2048;
constexpr int NH    = 16;
constexpr int HD    = 128;

typedef __attribute__((ext_vector_type(8))) short short8;   // 8 bf16 = MFMA A/B frag
typedef __attribute__((ext_vector_type(4))) float floatx4;  // MFMA C/D frag

static __device__ __forceinline__ ushort f2bf(float f) {
  union { float f; unsigned u; } v; v.f = f;
  unsigned r = (v.u + 0x7fffu + ((v.u >> 16) & 1u)) >> 16;  // RNE
  return (ushort)r;
}
static __device__ __forceinline__ ushort f2bf_fast(float f) {
  union { float f; unsigned u; } v; v.f = f;
  return (ushort)((v.u + 0x8000u) >> 16);  // round-to-nearest (ties away)
}

// async global->LDS, 16 B per lane; LDS dest = wave-uniform base + lane*16
static __device__ __forceinline__ void glds16(const ushort* g, ushort* l) {
  __builtin_amdgcn_global_load_lds(
      (const __attribute__((address_space(1))) void*)g,
      (__attribute__((address_space(3))) void*)l, 16, 0, 0);
}

// ---------------------------------------------------------------------------
// Conversion pre-pass: xb=bf16(x); Wq/Wk/Wv/Wo -> bf16.
// ---------------------------------------------------------------------------
static __device__ __forceinline__ void cvt4(ushort* dst, const float* src, size_t i) {
  const float4 v = ((const float4*)src)[i];
  ushort4 u = {f2bf(v.x), f2bf(v.y), f2bf(v.z), f2bf(v.w)};
  ((ushort4*)dst)[i] = u;
}

__global__ __launch_bounds__(256)
void convert_all(const float* __restrict__ x,
                 const float* __restrict__ wq, const float* __restrict__ wk,
                 const float* __restrict__ wv, const float* __restrict__ wo,
                 ushort* __restrict__ xb, ushort* __restrict__ wqb,
                 ushort* __restrict__ wkb, ushort* __restrict__ wvb,
                 ushort* __restrict__ wob) {
  const size_t gid = blockIdx.x * 256 + threadIdx.x;
  const size_t T = gridDim.x * 256;
  const size_t NX = (size_t)4096 * HID / 4;   // 2M float4
  const size_t NW = (size_t)HID * HID / 4;    // 1M float4
  for (size_t i = gid; i < NX; i += T) cvt4(xb, x, i);
  for (size_t i = gid; i < NW; i += T) {
    cvt4(wqb, wq, i);
    cvt4(wkb, wk, i);
    cvt4(wvb, wv, i);
    cvt4(wob, wo, i);
  }
}

// ---------------------------------------------------------------------------
// bf16 MFMA GEMM (m97 structure): C[m,n] = sum_k A[m,k]*W[n,k] + bias[n].
// 128x128 tile, BK=32, 256 thr (2x2 waves of 64x64), 16x16x32 MFMA.
// LDS [128][32] bf16, 16B chunks XOR-swizzled -> DMA-compatible + conflict-free.
// ---------------------------------------------------------------------------
template <bool BF16OUT>
__device__ __forceinline__
void gemm_core(const ushort* __restrict__ A, const ushort* __restrict__ W,
               const float* __restrict__ bias, void* __restrict__ Cv,
               int m0, int n0) {
  __shared__ __align__(16) ushort As[4096];   // 128x32
  __shared__ __align__(16) ushort Bs[4096];

  const int tid  = threadIdx.x;
  const int lane = tid & 63;
  const int w    = tid >> 6;
  const int wm   = w >> 1, wn = w & 1;
  const int n16  = lane & 15, q4 = lane >> 4;

  const int sr = lane >> 2;
  const int sc = (lane & 3) ^ ((lane >> 4) & 3);
  const ushort* ag0 = A + (size_t)(m0 + w*32 + sr) * HID + sc*8;
  const ushort* ag1 = ag0 + (size_t)16 * HID;
  const ushort* bg0 = W + (size_t)(n0 + w*32 + sr) * HID + sc*8;
  const ushort* bg1 = bg0 + (size_t)16 * HID;
  ushort* al0 = As + (w*2 + 0) * 512;
  ushort* al1 = As + (w*2 + 1) * 512;
  ushort* bl0 = Bs + (w*2 + 0) * 512;
  ushort* bl1 = Bs + (w*2 + 1) * 512;

  const int fp = n16*4 + (q4 ^ ((n16 >> 2) & 3));

  floatx4 acc[4][4];
  #pragma unroll
  for (int i = 0; i < 4; ++i)
    #pragma unroll
    for (int j = 0; j < 4; ++j) acc[i][j] = (floatx4)0.f;

  for (int kb0 = 0; kb0 < HID; kb0 += 32) {
    __syncthreads();
    glds16(ag0 + kb0, al0);
    glds16(ag1 + kb0, al1);
    glds16(bg0 + kb0, bl0);
    glds16(bg1 + kb0, bl1);
    __syncthreads();

    short8 af[4], bf[4];
    #pragma unroll
    for (int t = 0; t < 4; ++t) {
      af[t] = *(const short8*)&As[(wm*4 + t)*512 + fp*8];
      bf[t] = *(const short8*)&Bs[(wn*4 + t)*512 + fp*8];
    }
    #pragma unroll
    for (int mt = 0; mt < 4; ++mt)
      #pragma unroll
      for (int nt = 0; nt < 4; ++nt)
        acc[mt][nt] = __builtin_amdgcn_mfma_f32_16x16x32_bf16(af[mt], bf[nt], acc[mt][nt], 0, 0, 0);
  }

  float bv4[4];
  #pragma unroll
  for (int nt = 0; nt < 4; ++nt) bv4[nt] = bias[n0 + wn*64 + nt*16 + n16];
  #pragma unroll
  for (int mt = 0; mt < 4; ++mt)
    #pragma unroll
    for (int nt = 0; nt < 4; ++nt)
      #pragma unroll
      for (int r = 0; r < 4; ++r) {
        const int row = m0 + wm*64 + mt*16 + q4*4 + r;
        const int col = n0 + wn*64 + nt*16 + n16;
        if (BF16OUT)
          ((ushort*)Cv)[(size_t)row * HID + col] = f2bf(acc[mt][nt][r] + bv4[nt]);
        else
          ((float*)Cv)[(size_t)row * HID + col] = acc[mt][nt][r] + bv4[nt];
      }
}

__global__ __launch_bounds__(256)
void gemm_qkv(const ushort* __restrict__ xb,
              const ushort* __restrict__ wqb, const ushort* __restrict__ wkb,
              const ushort* __restrict__ wvb,
              const float* __restrict__ bq, const float* __restrict__ bk,
              const float* __restrict__ bv,
              ushort* __restrict__ qb, ushort* __restrict__ kb_, ushort* __restrict__ vb) {
  const ushort* W; const float* bias; ushort* C;
  if (blockIdx.z == 0)      { W = wqb; bias = bq; C = qb;  }
  else if (blockIdx.z == 1) { W = wkb; bias = bk; C = kb_; }
  else                      { W = wvb; bias = bv; C = vb;  }
  gemm_core<true>(xb, W, bias, C, blockIdx.y * 128, blockIdx.x * 128);
}

__global__ __launch_bounds__(256)
void gemm_o(const ushort* __restrict__ ao, const ushort* __restrict__ wob,
            const float* __restrict__ bo, float* __restrict__ out) {
  gemm_core<false>(ao, wob, bo, out, blockIdx.y * 128, blockIdx.x * 128);
}

// ---------------------------------------------------------------------------
// V transpose per head: vb[b][s][h*128+d] (bf16) -> vt[b][h][d][s] (bf16)
// 64x64 tiles through LDS, coalesced both sides.
// ---------------------------------------------------------------------------
__global__ __launch_bounds__(256)
void transpose_v(const ushort* __restrict__ vb, ushort* __restrict__ vt) {
  __shared__ ushort T[64][72];
  const int t  = threadIdx.x;
  const int bh = blockIdx.z;
  const int b = bh >> 4, h = bh & 15;
  const int s0 = blockIdx.x * 64;
  const int d0 = blockIdx.y * 64;
  {
    const int r = t >> 2, c = (t & 3) * 16;
    const ushort* src = vb + (size_t)(b*S_LEN + s0 + r)*HID + h*HD + d0 + c;
    *(uint4*)&T[r][c]     = *(const uint4*)src;
    *(uint4*)&T[r][c + 8] = *(const uint4*)(src + 8);
  }
  __syncthreads();
  {
    const int dd = t >> 2, c = (t & 3) * 16;
    ushort tmp[16];
    #pragma unroll
    for (int j = 0; j < 16; ++j) tmp[j] = T[c + j][dd];
    ushort* dst = vt + (size_t)((b*NH + h)*HD + d0 + dd)*S_LEN + s0 + c;
    *(uint4*)dst       = *(uint4*)tmp;
    *(uint4*)(dst + 8) = *(uint4*)(tmp + 8);
  }
}

// ---------------------------------------------------------------------------
// Flash attention v4: bf16 MFMA, fixed-max softmax, 32 q-rows/wave (2 m-frags),
// K and V^T staged via global_load_lds DMA with XOR-swizzled gather:
//   K tile  64 rows x 16 chunks: phys = row*16 + ((cl&8)|((cl^row)&7))
//   V^T tile 128 rows x 8 chunks: phys = row*8  + ((cl^row)&7)
// -> DMA-contiguous dest, conflict-free ds_read_b128 frags (each 16B slot mod 8
// hit exactly 8x per wave). P round-trips per-wave LDS (m120). Epilogue packs
// output through dead K/V LDS -> uint4 coalesced stores (fixes 84MB WRITE_SIZE).
// LDS: 16K (Ks) + 16K (Vs) + 18K (Ps) = 50 KB -> 2 blocks/CU at grid 512.
// ---------------------------------------------------------------------------
__global__ __launch_bounds__(256, 2)
void attn_mfma(const ushort* __restrict__ qb, const ushort* __restrict__ kbuf,
               const ushort* __restrict__ vtb, const float* __restrict__ mask,
               ushort* __restrict__ ao) {
  __shared__ __align__(16) ushort SM[25600];  // Ks[0,8192) Vs[8192,16384) Ps[16384,25600)

  const int tid  = threadIdx.x;
  const int w    = tid >> 6;
  const int lane = tid & 63;
  const int n16  = lane & 15;
  const int q4   = lane >> 4;
  const int n7   = n16 & 7;
  const int b  = blockIdx.y >> 4;
  const int h  = blockIdx.y & 15;
  const int q0 = blockIdx.x * 128;
  const float scale = 0.08838834764831845f;  // 1/sqrt(128)

  ushort* Ks = SM;
  ushort* Vs = SM + 8192;
  ushort* Pw = SM + 16384 + w * 2304;        // per-wave [32 rows][72]

  // Q A-frags, resident whole kernel: mt in {0,1}, rows w*32 + mt*16 + n16
  short8 aq[2][4];
  #pragma unroll
  for (int mt = 0; mt < 2; ++mt) {
    const ushort* qrow = qb + (size_t)(b*S_LEN + q0 + w*32 + mt*16 + n16)*HID + h*HD;
    #pragma unroll
    for (int kc = 0; kc < 4; ++kc)
      aq[mt][kc] = *(const short8*)(qrow + kc*32 + q4*8);
  }

  // DMA source gather pointers (4 calls each; swizzle baked into source addr)
  const ushort* ksrc[4];
  const ushort* vsrc[4];
  #pragma unroll
  for (int i = 0; i < 4; ++i) {
    const int p = (w*4 + i)*64 + lane;
    { const int rho = p >> 4, pc = p & 15;
      const int cl = (pc & 8) | ((pc ^ rho) & 7);
      ksrc[i] = kbuf + (size_t)(b*S_LEN + rho)*HID + h*HD + cl*8; }
    { const int rho = p >> 3, pc = p & 7;
      const int cl = (pc ^ rho) & 7;
      vsrc[i] = vtb + ((size_t)(b*NH + h)*HD + rho)*S_LEN + cl*8; }
  }

  floatx4 oacc[2][8];
  float lp[2][4];
  #pragma unroll
  for (int mt = 0; mt < 2; ++mt) {
    #pragma unroll
    for (int dt = 0; dt < 8; ++dt) oacc[mt][dt] = (floatx4)0.f;
    #pragma unroll
    for (int r = 0; r < 4; ++r) lp[mt][r] = 0.f;
  }

  for (int kb0 = 0; kb0 < S_LEN; kb0 += 64) {
    __syncthreads();  // prev tile's compute done
    #pragma unroll
    for (int i = 0; i < 4; ++i) {
      glds16(ksrc[i] + (size_t)kb0 * HID, Ks + (w*4 + i)*512);
      glds16(vsrc[i] + kb0,               Vs + (w*4 + i)*512);
    }
    __syncthreads();  // DMA drained (compiler emits vmcnt(0))

    // QK^T: D[qrow 32][kcol 64]; K-frags read once, reused across 2 m-tiles
    floatx4 acc[2][4];
    #pragma unroll
    for (int mt = 0; mt < 2; ++mt)
      #pragma unroll
      for (int nt = 0; nt < 4; ++nt) acc[mt][nt] = (floatx4)0.f;
    #pragma unroll
    for (int nt = 0; nt < 4; ++nt) {
      #pragma unroll
      for (int kc = 0; kc < 4; ++kc) {
        const int cl = kc*4 + q4;
        const int pc = (cl & 8) | ((cl ^ n7) & 7);
        const short8 bk = *(const short8*)&Ks[(nt*16 + n16)*128 + pc*8];
        acc[0][nt] = __builtin_amdgcn_mfma_f32_16x16x32_bf16(aq[0][kc], bk, acc[0][nt], 0, 0, 0);
        acc[1][nt] = __builtin_amdgcn_mfma_f32_16x16x32_bf16(aq[1][kc], bk, acc[1][nt], 0, 0, 0);
      }
    }

    // fixed-max softmax: p = exp(s*scale + mask); no reductions, no rescale
    float mk[4];
    #pragma unroll
    for (int nt = 0; nt < 4; ++nt)
      mk[nt] = mask[(size_t)b*S_LEN + kb0 + nt*16 + n16];

    #pragma unroll
    for (int mt = 0; mt < 2; ++mt)
      #pragma unroll
      for (int r = 0; r < 4; ++r) {
        float p[4];
        #pragma unroll
        for (int nt = 0; nt < 4; ++nt) p[nt] = __expf(acc[mt][nt][r] * scale + mk[nt]);
        lp[mt][r] += (p[0] + p[1]) + (p[2] + p[3]);
        #pragma unroll
        for (int nt = 0; nt < 4; ++nt)
          Pw[(mt*16 + q4*4 + r)*72 + nt*16 + n16] = f2bf_fast(p[nt]);
      }
    // per-wave Ps: same-wave write->read, compiler inserts lgkmcnt

    // PV: D[qrow 32][dd 128] += P[32x64] * V[64x128]; V-frags reused x2
    #pragma unroll
    for (int kc2 = 0; kc2 < 2; ++kc2) {
      const short8 ap0 = *(const short8*)&Pw[(0*16 + n16)*72 + kc2*32 + q4*8];
      const short8 ap1 = *(const short8*)&Pw[(1*16 + n16)*72 + kc2*32 + q4*8];
      const int clb = kc2*4 + q4;
      const int pcb = (clb ^ n7) & 7;
      #pragma unroll
      for (int dt = 0; dt < 8; ++dt) {
        const short8 bvf = *(const short8*)&Vs[(dt*16 + n16)*64 + pcb*8];
        oacc[0][dt] = __builtin_amdgcn_mfma_f32_16x16x32_bf16(ap0, bvf, oacc[0][dt], 0, 0, 0);
        oacc[1][dt] = __builtin_amdgcn_mfma_f32_16x16x32_bf16(ap1, bvf, oacc[1][dt], 0, 0, 0);
      }
    }
  }

  // one-time l reduction across the 16 lanes sharing each row
  #pragma unroll
  for (int mt = 0; mt < 2; ++mt)
    #pragma unroll
    for (int r = 0; r < 4; ++r) {
      float l = lp[mt][r];
      l += __shfl_xor(l, 1);
      l += __shfl_xor(l, 2);
      l += __shfl_xor(l, 4);
      l += __shfl_xor(l, 8);
      lp[mt][r] = 1.0f / l;
    }

  // Packed epilogue: dump per-wave [32][136] into dead K/V LDS, then uint4 stores
  __syncthreads();  // all waves done reading Ks/Vs
  ushort* dump = SM + w * 4352;
  #pragma unroll
  for (int mt = 0; mt < 2; ++mt)
    #pragma unroll
    for (int r = 0; r < 4; ++r) {
      const int row = mt*16 + q4*4 + r;
      #pragma unroll
      for (int dt = 0; dt < 8; ++dt)
        dump[row*136 + dt*16 + n16] = f2bf(oacc[mt][dt][r] * lp[mt][r]);
    }
  const int drow = lane >> 1, dhalf = lane & 1;   // 2 lanes per row, 128B each
  const size_t gbase = (size_t)(b*S_LEN + q0 + w*32 + drow)*HID + h*HD + dhalf*64;
  #pragma unroll
  for (int j = 0; j < 8; ++j)
    *(uint4*)&ao[gbase + j*8] = *(const uint4*)&dump[drow*136 + dhalf*64 + j*8];
}

// ---------------------------------------------------------------------------
extern "C" void kernel_launch(void* const* d_in, const int* in_sizes, int n_in,
                              void* d_out, int out_size, void* d_ws, size_t ws_size,
                              hipStream_t stream) {
  (void)n_in; (void)out_size; (void)ws_size;
  const float* x    = (const float*)d_in[0];
  const float* mask = (const float*)d_in[1];
  const float* Wq   = (const float*)d_in[2];
  const float* bq   = (const float*)d_in[3];
  const float* Wk   = (const float*)d_in[4];
  const float* bk   = (const float*)d_in[5];
  const float* Wv   = (const float*)d_in[6];
  const float* bv   = (const float*)d_in[7];
  const float* Wo   = (const float*)d_in[8];
  const float* bo   = (const float*)d_in[9];
  float* out = (float*)d_out;

  const int B = in_sizes[0] / (S_LEN * HID);   // 2
  const int M = B * S_LEN;                     // 4096
  const size_t MH = (size_t)M * HID;           // 8M
  const size_t WW = (size_t)HID * HID;         // 4M

  // ws layout (112 MB): xb | wqb wkb wvb wob | qb kbuf vb vt
  ushort* xb   = (ushort*)d_ws;       // 8M
  ushort* wqb  = xb   + MH;           // 4M each
  ushort* wkb  = wqb  + WW;
  ushort* wvb  = wkb  + WW;
  ushort* wob  = wvb  + WW;
  ushort* qb   = wob  + WW;           // 8M each
  ushort* kbuf = qb   + MH;
  ushort* vb   = kbuf + MH;
  ushort* vt   = vb   + MH;
  ushort* ao   = xb;                  // xb dead after gemm_qkv

  convert_all<<<512, 256, 0, stream>>>(x, Wq, Wk, Wv, Wo, xb, wqb, wkb, wvb, wob);
  gemm_qkv<<<dim3(HID/128, M/128, 3), 256, 0, stream>>>(xb, wqb, wkb, wvb, bq, bk, bv, qb, kbuf, vb);
  transpose_v<<<dim3(S_LEN/64, HD/64, B*NH), 256, 0, stream>>>(vb, vt);
  attn_mfma<<<dim3(S_LEN/128, B*NH), 256, 0, stream>>>(qb, kbuf, vt, mask, ao);
  gemm_o<<<dim3(HID/128, M/128), 256, 0, stream>>>(ao, wob, bo, out);
}